// Round 13
// baseline (165.326 us; speedup 1.0000x reference)
//
#include <hip/hip_runtime.h>
#include <hip/hip_cooperative_groups.h>
#include <math.h>

namespace cg = cooperative_groups;

#define N_NODES 50000
#define DEG 32
#define WIDTH 128
#define BATCH 4096
#define EPS 1e-12f
#define NBLK 256

typedef __attribute__((ext_vector_type(8))) short short8;           // 8 bf16
typedef __attribute__((ext_vector_type(4))) float f32x4;            // MFMA acc
typedef unsigned short u16;

__device__ __forceinline__ u16 f2bf(float f) {
    unsigned x;
    __builtin_memcpy(&x, &f, 4);
    unsigned r = (x + 0x7fff + ((x >> 16) & 1)) >> 16;  // RNE
    return (u16)r;
}
__device__ __forceinline__ unsigned pkmax_u16(unsigned a, unsigned b) {
    unsigned lo = (a & 0xffffu) > (b & 0xffffu) ? (a & 0xffffu) : (b & 0xffffu);
    unsigned hi = (a >> 16) > (b >> 16) ? (a >> 16) : (b >> 16);
    return lo | (hi << 16);
}
__device__ __forceinline__ short8 cvt8(const float* __restrict__ p) {
    float4 a0 = *(const float4*)p;
    float4 a1 = *(const float4*)(p + 4);
    short8 v;
    v[0] = (short)f2bf(a0.x); v[1] = (short)f2bf(a0.y);
    v[2] = (short)f2bf(a0.z); v[3] = (short)f2bf(a0.w);
    v[4] = (short)f2bf(a1.x); v[5] = (short)f2bf(a1.y);
    v[6] = (short)f2bf(a1.z); v[7] = (short)f2bf(a1.w);
    return v;
}

// ======================= FALLBACK KERNELS (verbatim r9, 55.4 µs) =======================
__global__ __launch_bounds__(512) void head_k(
    const float* __restrict__ feats, const float* __restrict__ W_agg,
    const float* __restrict__ W_lin, const float* __restrict__ b_agg,
    const int* __restrict__ node_idx, int* __restrict__ inv,
    u16* __restrict__ M0b, float* __restrict__ S) {
    __shared__ u16 wa[128 * 128];
    __shared__ u16 wl[128 * 128];
    int tid = threadIdx.x;
    int gid = blockIdx.x * 512 + tid;
    if (gid < BATCH) atomicMax(&inv[node_idx[gid]], gid);
#pragma unroll
    for (int it = 0; it < 4; ++it) {
        int c = tid + it * 512;
        int r = c >> 4, ch = c & 15;
        int sw = (ch * 16) ^ ((r & 7) << 4);
        *(short8*)((char*)wa + r * 256 + sw) = cvt8(W_agg + (size_t)r * 128 + ch * 8);
        *(short8*)((char*)wl + r * 256 + sw) = cvt8(W_lin + (size_t)r * 256 + ch * 8);
    }
    int w = tid >> 6, l = tid & 63, li = l & 15, kq = l >> 4;
    int r0 = blockIdx.x * 16;
    int arow = r0 + li;
    int col = w * 16 + li;
    short8 a[4];
#pragma unroll
    for (int kk = 0; kk < 4; ++kk)
        a[kk] = cvt8(feats + (size_t)arow * 128 + kk * 32 + kq * 8);
    __syncthreads();
    f32x4 am = (f32x4){0,0,0,0}, as = (f32x4){0,0,0,0};
#pragma unroll
    for (int kk = 0; kk < 4; ++kk) {
        int sw = (kk * 64 + kq * 16) ^ ((col & 7) << 4);
        short8 bm = *(const short8*)((char*)wa + col * 256 + sw);
        am = __builtin_amdgcn_mfma_f32_16x16x32_bf16(a[kk], bm, am, 0, 0, 0);
        short8 bs = *(const short8*)((char*)wl + col * 256 + sw);
        as = __builtin_amdgcn_mfma_f32_16x16x32_bf16(a[kk], bs, as, 0, 0, 0);
    }
    float ba = b_agg[col];
#pragma unroll
    for (int r = 0; r < 4; ++r) {
        int grow = r0 + kq * 4 + r;
        float t = am[r] + ba;
        t = t > 0.f ? t : 0.f;
        M0b[(size_t)grow * 128 + col] = f2bf(t);
        S[(size_t)grow * 128 + col] = as[r];
    }
}

__global__ __launch_bounds__(256) void agg1_k(
    const int* __restrict__ nbd, const int* __restrict__ inv,
    const u16* __restrict__ M0b, const float* __restrict__ b_agg,
    unsigned* __restrict__ AGG1u) {
    int wave = blockIdx.x * 4 + (threadIdx.x >> 6);
    int lane = threadIdx.x & 63;
    int n0 = wave * 2;
    int nb = nbd[(size_t)n0 * DEG + lane];
    int bi = inv[nb];
    unsigned long long warm = __ballot(bi >= 0);
    unsigned m0 = (unsigned)warm;
    unsigned m1 = (unsigned)(warm >> 32);
    float ba0 = b_agg[2 * lane], ba1 = b_agg[2 * lane + 1];
    ba0 = ba0 > 0.f ? ba0 : 0.f;
    ba1 = ba1 > 0.f ? ba1 : 0.f;
    unsigned rb = (unsigned)f2bf(ba0) | ((unsigned)f2bf(ba1) << 16);
    unsigned acc0 = (m0 != 0xffffffffu) ? rb : 0u;
    while (m0) {
        int pos = __builtin_ctz(m0);
        m0 &= m0 - 1;
        int bib = __shfl(bi, pos);
        acc0 = pkmax_u16(acc0, ((const unsigned*)(M0b + (size_t)bib * WIDTH))[lane]);
    }
    AGG1u[(size_t)n0 * 64 + lane] = acc0;
    unsigned acc1 = (m1 != 0xffffffffu) ? rb : 0u;
    while (m1) {
        int pos = __builtin_ctz(m1);
        m1 &= m1 - 1;
        int bib = __shfl(bi, 32 + pos);
        acc1 = pkmax_u16(acc1, ((const unsigned*)(M0b + (size_t)bib * WIDTH))[lane]);
    }
    AGG1u[(size_t)(n0 + 1) * 64 + lane] = acc1;
}

__global__ __launch_bounds__(512) void hop1mm_k(
    const u16* __restrict__ AGG1, const int* __restrict__ inv,
    const float* __restrict__ S, const float* __restrict__ b_lin,
    const float* __restrict__ b_agg,
    const float* __restrict__ W_lin, const float* __restrict__ W_agg,
    u16* __restrict__ H1g, u16* __restrict__ M1) {
    __shared__ u16 wlds[128 * 128];
    __shared__ u16 h1t[128 * 136];
    int tid = threadIdx.x;
    int w = tid >> 6, l = tid & 63, li = l & 15, kq = l >> 4;
    int row0 = blockIdx.x * 128;
    int lrow = w * 16 + li;
    int arow = row0 + lrow;
    if (arow > N_NODES - 1) arow = N_NODES - 1;
    short8 af[4];
#pragma unroll
    for (int kk = 0; kk < 4; ++kk)
        af[kk] = *(const short8*)(AGG1 + (size_t)arow * 128 + kk * 32 + kq * 8);
#pragma unroll
    for (int it = 0; it < 4; ++it) {
        int c = tid + it * 512;
        int r = c >> 4, ch = c & 15;
        *(short8*)((char*)wlds + r * 256 + ((ch * 16) ^ ((r & 7) << 4))) =
            cvt8(W_lin + (size_t)r * 256 + 128 + ch * 8);
    }
    __syncthreads();
    f32x4 h[8];
#pragma unroll
    for (int n = 0; n < 8; ++n) h[n] = (f32x4){0,0,0,0};
#pragma unroll
    for (int kk = 0; kk < 4; ++kk)
#pragma unroll
        for (int n = 0; n < 8; ++n) {
            int col = n * 16 + li;
            short8 b = *(const short8*)((char*)wlds + col * 256 +
                                        ((kk * 64 + kq * 16) ^ ((col & 7) << 4)));
            h[n] = __builtin_amdgcn_mfma_f32_16x16x32_bf16(af[kk], b, h[n], 0, 0, 0);
        }
    float blv[8];
#pragma unroll
    for (int n = 0; n < 8; ++n) blv[n] = b_lin[n * 16 + li];
#pragma unroll
    for (int r = 0; r < 4; ++r) {
        int lr = w * 16 + kq * 4 + r;
        int grow = row0 + lr;
        int growc = grow < N_NODES ? grow : N_NODES - 1;
        int bi = inv[growc];
        float v[8];
#pragma unroll
        for (int n = 0; n < 8; ++n) v[n] = h[n][r] + blv[n];
        if (bi >= 0) {
#pragma unroll
            for (int n = 0; n < 8; ++n) v[n] += S[(size_t)bi * 128 + n * 16 + li];
        }
        float p = 0.f;
#pragma unroll
        for (int n = 0; n < 8; ++n) {
            v[n] = fmaxf(v[n], 0.f);
            p += v[n] * v[n];
        }
        p += __shfl_xor(p, 1);
        p += __shfl_xor(p, 2);
        p += __shfl_xor(p, 4);
        p += __shfl_xor(p, 8);
        float sc = 1.0f / fmaxf(sqrtf(p), EPS);
        u16 vb[8];
#pragma unroll
        for (int n = 0; n < 8; ++n) vb[n] = f2bf(v[n] * sc);
        if (grow < N_NODES && bi >= 0) {
#pragma unroll
            for (int n = 0; n < 8; ++n) H1g[(size_t)grow * 128 + n * 16 + li] = vb[n];
        }
#pragma unroll
        for (int n = 0; n < 8; ++n) h1t[lr * 136 + n * 16 + li] = vb[n];
    }
    __syncthreads();
#pragma unroll
    for (int it = 0; it < 4; ++it) {
        int c = tid + it * 512;
        int r = c >> 4, ch = c & 15;
        *(short8*)((char*)wlds + r * 256 + ((ch * 16) ^ ((r & 7) << 4))) =
            cvt8(W_agg + (size_t)r * 128 + ch * 8);
    }
    __syncthreads();
    short8 af2[4];
#pragma unroll
    for (int kk = 0; kk < 4; ++kk)
        af2[kk] = *(const short8*)(h1t + lrow * 136 + kk * 32 + kq * 8);
    f32x4 m[8];
#pragma unroll
    for (int n = 0; n < 8; ++n) m[n] = (f32x4){0,0,0,0};
#pragma unroll
    for (int kk = 0; kk < 4; ++kk)
#pragma unroll
        for (int n = 0; n < 8; ++n) {
            int col = n * 16 + li;
            short8 b = *(const short8*)((char*)wlds + col * 256 +
                                        ((kk * 64 + kq * 16) ^ ((col & 7) << 4)));
            m[n] = __builtin_amdgcn_mfma_f32_16x16x32_bf16(af2[kk], b, m[n], 0, 0, 0);
        }
    float bav[8];
#pragma unroll
    for (int n = 0; n < 8; ++n) bav[n] = b_agg[n * 16 + li];
#pragma unroll
    for (int r = 0; r < 4; ++r) {
        int grow = row0 + w * 16 + kq * 4 + r;
        if (grow < N_NODES) {
#pragma unroll
            for (int n = 0; n < 8; ++n) {
                float t = m[n][r] + bav[n];
                t = t > 0.f ? t : 0.f;
                M1[(size_t)grow * 128 + n * 16 + li] = f2bf(t);
            }
        }
    }
}

__global__ __launch_bounds__(512) void tail_k(
    const int* __restrict__ nbd, const int* __restrict__ node_idx,
    const u16* __restrict__ H1g, const u16* __restrict__ M1,
    const float* __restrict__ W_lin, const float* __restrict__ b_lin,
    float* __restrict__ out) {
    __shared__ u16 wt[128 * 256];
    __shared__ u16 ab2[16 * 264];
    __shared__ float pn[128];
    __shared__ float pnt[16];
    int tid = threadIdx.x;
    int w = tid >> 6, l = tid & 63, li = l & 15, kq = l >> 4;
    int row0 = blockIdx.x * 16;
#pragma unroll
    for (int it = 0; it < 8; ++it) {
        int c = tid + it * 512;
        int r = c >> 5, ch = c & 31;
        *(short8*)((char*)wt + r * 512 + ((ch * 16) ^ ((r & 7) << 4))) =
            cvt8(W_lin + (size_t)r * 256 + ch * 8);
    }
#pragma unroll
    for (int rr = 0; rr < 2; ++rr) {
        int lr = w * 2 + rr;
        int i = row0 + lr;
        int n = node_idx[i];
        unsigned hv = ((const unsigned*)(H1g + (size_t)n * 128))[l];
        *(unsigned*)((char*)ab2 + lr * 528 + l * 4) = hv;
        int nb = (l < DEG) ? nbd[(size_t)n * DEG + l] : 0;
        unsigned acc = 0;
#pragma unroll
        for (int j = 0; j < DEG; ++j) {
            int bib = __shfl(nb, j);
            acc = pkmax_u16(acc, ((const unsigned*)(M1 + (size_t)bib * 128))[l]);
        }
        *(unsigned*)((char*)ab2 + lr * 528 + 256 + l * 4) = acc;
    }
    __syncthreads();
    int col = w * 16 + li;
    f32x4 acc4 = (f32x4){0,0,0,0};
#pragma unroll
    for (int kk = 0; kk < 8; ++kk) {
        short8 a = *(const short8*)((char*)ab2 + li * 528 + kk * 64 + kq * 16);
        short8 b = *(const short8*)((char*)wt + col * 512 +
                                    ((kk * 64 + kq * 16) ^ ((col & 7) << 4)));
        acc4 = __builtin_amdgcn_mfma_f32_16x16x32_bf16(a, b, acc4, 0, 0, 0);
    }
    float bl = b_lin[col];
    float v[4];
#pragma unroll
    for (int r = 0; r < 4; ++r) {
        v[r] = fmaxf(acc4[r] + bl, 0.f);
        float p = v[r] * v[r];
        p += __shfl_xor(p, 1);
        p += __shfl_xor(p, 2);
        p += __shfl_xor(p, 4);
        p += __shfl_xor(p, 8);
        if (li == 0) pn[w * 16 + kq * 4 + r] = p;
    }
    __syncthreads();
    if (tid < 16) {
        float s = 0.f;
#pragma unroll
        for (int ww = 0; ww < 8; ++ww) s += pn[ww * 16 + tid];
        pnt[tid] = s;
    }
    __syncthreads();
#pragma unroll
    for (int r = 0; r < 4; ++r) {
        int row = kq * 4 + r;
        float sc = 1.0f / fmaxf(sqrtf(pnt[row]), EPS);
        out[(size_t)(row0 + row) * 128 + col] = v[r] * sc;
    }
}

// ======================= COOPERATIVE FUSED KERNEL (256 blocks, 1/CU) =======================
__global__ __launch_bounds__(512) void fused_k(
    const int* __restrict__ nbd, const int* __restrict__ node_idx,
    const float* __restrict__ feats, const float* __restrict__ W_agg,
    const float* __restrict__ b_agg, const float* __restrict__ W_lin,
    const float* __restrict__ b_lin, int* __restrict__ inv,
    u16* __restrict__ M0b, float* __restrict__ S, unsigned* __restrict__ AGG1u,
    u16* __restrict__ H1g, u16* __restrict__ M1, float* __restrict__ out) {
    __shared__ __align__(16) char lds[67584];
    cg::grid_group grid = cg::this_grid();

    const int tid = threadIdx.x;
    const int bid = blockIdx.x;
    const int w = tid >> 6, l = tid & 63, li = l & 15, kq = l >> 4;

    // ---- P0: scatter inv + head GEMM (256 tiles exactly) ----
    {
        int gid = bid * 512 + tid;
        if (gid < BATCH) atomicMax(&inv[node_idx[gid]], gid);
    }
    {
        u16* wa = (u16*)lds;
        u16* wl = (u16*)(lds + 32768);
#pragma unroll
        for (int it = 0; it < 4; ++it) {
            int c = tid + it * 512;
            int r = c >> 4, ch = c & 15;
            int sw = (ch * 16) ^ ((r & 7) << 4);
            *(short8*)((char*)wa + r * 256 + sw) = cvt8(W_agg + (size_t)r * 128 + ch * 8);
            *(short8*)((char*)wl + r * 256 + sw) = cvt8(W_lin + (size_t)r * 256 + ch * 8);
        }
        int r0 = bid * 16;
        int arow = r0 + li;
        int col = w * 16 + li;
        short8 a[4];
#pragma unroll
        for (int kk = 0; kk < 4; ++kk)
            a[kk] = cvt8(feats + (size_t)arow * 128 + kk * 32 + kq * 8);
        __syncthreads();
        f32x4 am = (f32x4){0,0,0,0}, as = (f32x4){0,0,0,0};
#pragma unroll
        for (int kk = 0; kk < 4; ++kk) {
            int sw = (kk * 64 + kq * 16) ^ ((col & 7) << 4);
            short8 bm = *(const short8*)((char*)wa + col * 256 + sw);
            am = __builtin_amdgcn_mfma_f32_16x16x32_bf16(a[kk], bm, am, 0, 0, 0);
            short8 bs = *(const short8*)((char*)wl + col * 256 + sw);
            as = __builtin_amdgcn_mfma_f32_16x16x32_bf16(a[kk], bs, as, 0, 0, 0);
        }
        float ba = b_agg[col];
#pragma unroll
        for (int r = 0; r < 4; ++r) {
            int grow = r0 + kq * 4 + r;
            float t = am[r] + ba;
            t = t > 0.f ? t : 0.f;
            M0b[(size_t)grow * 128 + col] = f2bf(t);
            S[(size_t)grow * 128 + col] = as[r];
        }
    }
    grid.sync();

    // ---- P1: agg1 — grid-strided wave per node-pair ----
    {
        int nw = gridDim.x * 8;
        int wgid = bid * 8 + w;
        float ba0 = b_agg[2 * l], ba1 = b_agg[2 * l + 1];
        ba0 = ba0 > 0.f ? ba0 : 0.f;
        ba1 = ba1 > 0.f ? ba1 : 0.f;
        unsigned rb = (unsigned)f2bf(ba0) | ((unsigned)f2bf(ba1) << 16);
        for (int p = wgid; p < N_NODES / 2; p += nw) {
            int n0 = p * 2;
            int nb = nbd[(size_t)n0 * DEG + l];
            int bi = inv[nb];
            unsigned long long warm = __ballot(bi >= 0);
            unsigned m0 = (unsigned)warm;
            unsigned m1m = (unsigned)(warm >> 32);
            unsigned acc0 = (m0 != 0xffffffffu) ? rb : 0u;
            while (m0) {
                int pos = __builtin_ctz(m0);
                m0 &= m0 - 1;
                int bib = __shfl(bi, pos);
                acc0 = pkmax_u16(acc0, ((const unsigned*)(M0b + (size_t)bib * WIDTH))[l]);
            }
            AGG1u[(size_t)n0 * 64 + l] = acc0;
            unsigned acc1 = (m1m != 0xffffffffu) ? rb : 0u;
            while (m1m) {
                int pos = __builtin_ctz(m1m);
                m1m &= m1m - 1;
                int bib = __shfl(bi, 32 + pos);
                acc1 = pkmax_u16(acc1, ((const unsigned*)(M0b + (size_t)bib * WIDTH))[l]);
            }
            AGG1u[(size_t)(n0 + 1) * 64 + l] = acc1;
        }
    }
    grid.sync();

    // ---- P2: hop1mm — fused double GEMM, grid-stride over 391 tiles ----
    for (int t = bid; t < (N_NODES + 127) / 128; t += NBLK) {
        __syncthreads();   // protect LDS reuse across tile iterations
        u16* wlds = (u16*)lds;
        u16* h1t = (u16*)(lds + 32768);
        int row0 = t * 128;
        int lrow = w * 16 + li;
        int arow = row0 + lrow;
        if (arow > N_NODES - 1) arow = N_NODES - 1;
        short8 af[4];
#pragma unroll
        for (int kk = 0; kk < 4; ++kk)
            af[kk] = *(const short8*)((const u16*)AGG1u + (size_t)arow * 128 + kk * 32 + kq * 8);
#pragma unroll
        for (int it = 0; it < 4; ++it) {
            int c = tid + it * 512;
            int r = c >> 4, ch = c & 15;
            *(short8*)((char*)wlds + r * 256 + ((ch * 16) ^ ((r & 7) << 4))) =
                cvt8(W_lin + (size_t)r * 256 + 128 + ch * 8);
        }
        __syncthreads();
        f32x4 h[8];
#pragma unroll
        for (int n = 0; n < 8; ++n) h[n] = (f32x4){0,0,0,0};
#pragma unroll
        for (int kk = 0; kk < 4; ++kk)
#pragma unroll
            for (int n = 0; n < 8; ++n) {
                int col = n * 16 + li;
                short8 b = *(const short8*)((char*)wlds + col * 256 +
                                            ((kk * 64 + kq * 16) ^ ((col & 7) << 4)));
                h[n] = __builtin_amdgcn_mfma_f32_16x16x32_bf16(af[kk], b, h[n], 0, 0, 0);
            }
        float blv[8];
#pragma unroll
        for (int n = 0; n < 8; ++n) blv[n] = b_lin[n * 16 + li];
#pragma unroll
        for (int r = 0; r < 4; ++r) {
            int lr = w * 16 + kq * 4 + r;
            int grow = row0 + lr;
            int growc = grow < N_NODES ? grow : N_NODES - 1;
            int bi = inv[growc];
            float v[8];
#pragma unroll
            for (int n = 0; n < 8; ++n) v[n] = h[n][r] + blv[n];
            if (bi >= 0) {
#pragma unroll
                for (int n = 0; n < 8; ++n) v[n] += S[(size_t)bi * 128 + n * 16 + li];
            }
            float p = 0.f;
#pragma unroll
            for (int n = 0; n < 8; ++n) {
                v[n] = fmaxf(v[n], 0.f);
                p += v[n] * v[n];
            }
            p += __shfl_xor(p, 1);
            p += __shfl_xor(p, 2);
            p += __shfl_xor(p, 4);
            p += __shfl_xor(p, 8);
            float sc = 1.0f / fmaxf(sqrtf(p), EPS);
            u16 vb[8];
#pragma unroll
            for (int n = 0; n < 8; ++n) vb[n] = f2bf(v[n] * sc);
            if (grow < N_NODES && bi >= 0) {
#pragma unroll
                for (int n = 0; n < 8; ++n) H1g[(size_t)grow * 128 + n * 16 + li] = vb[n];
            }
#pragma unroll
            for (int n = 0; n < 8; ++n) h1t[lr * 136 + n * 16 + li] = vb[n];
        }
        __syncthreads();
#pragma unroll
        for (int it = 0; it < 4; ++it) {
            int c = tid + it * 512;
            int r = c >> 4, ch = c & 15;
            *(short8*)((char*)wlds + r * 256 + ((ch * 16) ^ ((r & 7) << 4))) =
                cvt8(W_agg + (size_t)r * 128 + ch * 8);
        }
        __syncthreads();
        short8 af2[4];
#pragma unroll
        for (int kk = 0; kk < 4; ++kk)
            af2[kk] = *(const short8*)(h1t + lrow * 136 + kk * 32 + kq * 8);
        f32x4 m[8];
#pragma unroll
        for (int n = 0; n < 8; ++n) m[n] = (f32x4){0,0,0,0};
#pragma unroll
        for (int kk = 0; kk < 4; ++kk)
#pragma unroll
            for (int n = 0; n < 8; ++n) {
                int col = n * 16 + li;
                short8 b = *(const short8*)((char*)wlds + col * 256 +
                                            ((kk * 64 + kq * 16) ^ ((col & 7) << 4)));
                m[n] = __builtin_amdgcn_mfma_f32_16x16x32_bf16(af2[kk], b, m[n], 0, 0, 0);
            }
        float bav[8];
#pragma unroll
        for (int n = 0; n < 8; ++n) bav[n] = b_agg[n * 16 + li];
#pragma unroll
        for (int r = 0; r < 4; ++r) {
            int grow = row0 + w * 16 + kq * 4 + r;
            if (grow < N_NODES) {
#pragma unroll
                for (int n = 0; n < 8; ++n) {
                    float t2 = m[n][r] + bav[n];
                    t2 = t2 > 0.f ? t2 : 0.f;
                    M1[(size_t)grow * 128 + n * 16 + li] = f2bf(t2);
                }
            }
        }
    }
    grid.sync();

    // ---- P3: tail — gather + K=256 GEMM with W in two 32KB k-half stages ----
    {
        u16* wt = (u16*)lds;
        u16* ab2 = (u16*)(lds + 32768);
        float* pn = (float*)(lds + 32768 + 8448);
        float* pnt = (float*)(lds + 32768 + 8448 + 512);
        int row0 = bid * 16;
#pragma unroll
        for (int it = 0; it < 4; ++it) {
            int c = tid + it * 512;
            int r = c >> 4, ch = c & 15;
            *(short8*)((char*)wt + r * 256 + ((ch * 16) ^ ((r & 7) << 4))) =
                cvt8(W_lin + (size_t)r * 256 + ch * 8);
        }
#pragma unroll
        for (int rr = 0; rr < 2; ++rr) {
            int lr = w * 2 + rr;
            int i = row0 + lr;
            int n = node_idx[i];
            unsigned hv = ((const unsigned*)(H1g + (size_t)n * 128))[l];
            *(unsigned*)((char*)ab2 + lr * 528 + l * 4) = hv;
            int nb = (l < DEG) ? nbd[(size_t)n * DEG + l] : 0;
            unsigned acc = 0;
#pragma unroll
            for (int j = 0; j < DEG; ++j) {
                int bib = __shfl(nb, j);
                acc = pkmax_u16(acc, ((const unsigned*)(M1 + (size_t)bib * 128))[l]);
            }
            *(unsigned*)((char*)ab2 + lr * 528 + 256 + l * 4) = acc;
        }
        __syncthreads();
        int col = w * 16 + li;
        f32x4 acc4 = (f32x4){0,0,0,0};
#pragma unroll
        for (int kk = 0; kk < 4; ++kk) {
            short8 a = *(const short8*)((char*)ab2 + li * 528 + kk * 64 + kq * 16);
            short8 b = *(const short8*)((char*)wt + col * 256 +
                                        ((kk * 64 + kq * 16) ^ ((col & 7) << 4)));
            acc4 = __builtin_amdgcn_mfma_f32_16x16x32_bf16(a, b, acc4, 0, 0, 0);
        }
        __syncthreads();
#pragma unroll
        for (int it = 0; it < 4; ++it) {
            int c = tid + it * 512;
            int r = c >> 4, ch = c & 15;
            *(short8*)((char*)wt + r * 256 + ((ch * 16) ^ ((r & 7) << 4))) =
                cvt8(W_lin + (size_t)r * 256 + 128 + ch * 8);
        }
        __syncthreads();
#pragma unroll
        for (int kk = 0; kk < 4; ++kk) {
            short8 a = *(const short8*)((char*)ab2 + li * 528 + 256 + kk * 64 + kq * 16);
            short8 b = *(const short8*)((char*)wt + col * 256 +
                                        ((kk * 64 + kq * 16) ^ ((col & 7) << 4)));
            acc4 = __builtin_amdgcn_mfma_f32_16x16x32_bf16(a, b, acc4, 0, 0, 0);
        }
        float bl = b_lin[col];
        float v[4];
#pragma unroll
        for (int r = 0; r < 4; ++r) {
            v[r] = fmaxf(acc4[r] + bl, 0.f);
            float p = v[r] * v[r];
            p += __shfl_xor(p, 1);
            p += __shfl_xor(p, 2);
            p += __shfl_xor(p, 4);
            p += __shfl_xor(p, 8);
            if (li == 0) pn[w * 16 + kq * 4 + r] = p;
        }
        __syncthreads();
        if (tid < 16) {
            float s = 0.f;
#pragma unroll
            for (int ww = 0; ww < 8; ++ww) s += pn[ww * 16 + tid];
            pnt[tid] = s;
        }
        __syncthreads();
#pragma unroll
        for (int r = 0; r < 4; ++r) {
            int row = kq * 4 + r;
            float sc = 1.0f / fmaxf(sqrtf(pnt[row]), EPS);
            out[(size_t)(row0 + row) * 128 + col] = v[r] * sc;
        }
    }
}

// ---------------- launch ----------------
extern "C" void kernel_launch(void* const* d_in, const int* in_sizes, int n_in,
                              void* d_out, int out_size, void* d_ws, size_t ws_size,
                              hipStream_t stream) {
    const int*   nbd      = (const int*)d_in[0];
    const int*   node_idx = (const int*)d_in[1];
    const float* feats    = (const float*)d_in[2];
    const float* W_agg    = (const float*)d_in[3];
    const float* b_agg    = (const float*)d_in[4];
    const float* W_lin    = (const float*)d_in[5];
    const float* b_lin    = (const float*)d_in[6];
    float* out = (float*)d_out;

    char* base = (char*)d_ws;
    size_t off = 0;
    int* inv       = (int*)(base + off);      off += 50048 * 4;
    u16* M0b       = (u16*)(base + off);      off += (size_t)BATCH * 128 * 2;
    float* S       = (float*)(base + off);    off += (size_t)BATCH * 128 * 4;
    unsigned* AGG1 = (unsigned*)(base + off); off += (size_t)N_NODES * 128 * 2;
    u16* H1g       = (u16*)(base + off);      off += (size_t)N_NODES * 128 * 2;
    u16* M1        = (u16*)(base + off);      off += (size_t)N_NODES * 128 * 2;

    hipMemsetAsync(inv, 0xFF, 50048 * 4, stream);   // inv = -1

    void* args[] = {
        (void*)&nbd, (void*)&node_idx, (void*)&feats, (void*)&W_agg, (void*)&b_agg,
        (void*)&W_lin, (void*)&b_lin, (void*)&inv, (void*)&M0b, (void*)&S,
        (void*)&AGG1, (void*)&H1g, (void*)&M1, (void*)&out
    };
    hipError_t err = hipLaunchCooperativeKernel((const void*)fused_k, dim3(NBLK),
                                                dim3(512), args, 0, stream);
    if (err != hipSuccess) {
        // deterministic fallback: proven r9 4-kernel sequence
        head_k<<<BATCH / 16, 512, 0, stream>>>(feats, W_agg, W_lin, b_agg,
                                               node_idx, inv, M0b, S);
        agg1_k<<<N_NODES / 8, 256, 0, stream>>>(nbd, inv, (const u16*)M0b, b_agg, AGG1);
        hop1mm_k<<<(N_NODES + 127) / 128, 512, 0, stream>>>(
            (const u16*)AGG1, inv, S, b_lin, b_agg, W_lin, W_agg, H1g, M1);
        tail_k<<<BATCH / 16, 512, 0, stream>>>(nbd, node_idx, H1g, M1, W_lin, b_lin, out);
    }
}

// Round 14
// 61.031 us; speedup vs baseline: 2.7089x; 2.7089x over previous
//
#include <hip/hip_runtime.h>
#include <math.h>

#define N_NODES 50000
#define DEG 32
#define WIDTH 128
#define BATCH 4096
#define EPS 1e-12f

typedef __attribute__((ext_vector_type(8))) short short8;           // 8 bf16
typedef __attribute__((ext_vector_type(4))) float f32x4;            // MFMA acc
typedef unsigned short u16;

__device__ __forceinline__ u16 f2bf(float f) {
    unsigned x;
    __builtin_memcpy(&x, &f, 4);
    unsigned r = (x + 0x7fff + ((x >> 16) & 1)) >> 16;  // RNE
    return (u16)r;
}
__device__ __forceinline__ unsigned pkmax_u16(unsigned a, unsigned b) {
    unsigned lo = (a & 0xffffu) > (b & 0xffffu) ? (a & 0xffffu) : (b & 0xffffu);
    unsigned hi = (a >> 16) > (b >> 16) ? (a >> 16) : (b >> 16);
    return lo | (hi << 16);
}
// convert 8 consecutive f32 to a bf16 short8 fragment
__device__ __forceinline__ short8 cvt8(const float* __restrict__ p) {
    float4 a0 = *(const float4*)p;
    float4 a1 = *(const float4*)(p + 4);
    short8 v;
    v[0] = (short)f2bf(a0.x); v[1] = (short)f2bf(a0.y);
    v[2] = (short)f2bf(a0.z); v[3] = (short)f2bf(a0.w);
    v[4] = (short)f2bf(a1.x); v[5] = (short)f2bf(a1.y);
    v[6] = (short)f2bf(a1.z); v[7] = (short)f2bf(a1.w);
    return v;
}

// ---------------- head: scatter inv; M0b(bf16)=relu(feats@Wagg.T+b_agg); S(f32)=feats@Wself.T ----
// 256 blocks x 512 thr. Block 0 additionally dumps bf16 W copies to ws for later kernels.
__global__ __launch_bounds__(512) void head_k(
    const float* __restrict__ feats, const float* __restrict__ W_agg,
    const float* __restrict__ W_lin, const float* __restrict__ b_agg,
    const int* __restrict__ node_idx, int* __restrict__ inv,
    u16* __restrict__ M0b, float* __restrict__ S,
    u16* __restrict__ Wab_ws, u16* __restrict__ Wlb_ws) {
    __shared__ u16 wa[128 * 128];   // 32KB: W_agg swizzled
    __shared__ u16 wl[128 * 128];   // 32KB: W_lin k<128 (Wself) swizzled

    int tid = threadIdx.x;
    int gid = blockIdx.x * 512 + tid;
    if (gid < BATCH) atomicMax(&inv[node_idx[gid]], gid);  // last-write-wins scatter

#pragma unroll
    for (int it = 0; it < 4; ++it) {
        int c = tid + it * 512;            // 0..2047: 128 rows x 16 chunks(16B)
        int r = c >> 4, ch = c & 15;
        int sw = (ch * 16) ^ ((r & 7) << 4);
        *(short8*)((char*)wa + r * 256 + sw) = cvt8(W_agg + (size_t)r * 128 + ch * 8);
        *(short8*)((char*)wl + r * 256 + sw) = cvt8(W_lin + (size_t)r * 256 + ch * 8);
    }

    int w = tid >> 6, l = tid & 63, li = l & 15, kq = l >> 4;
    int r0 = blockIdx.x * 16;
    int arow = r0 + li;
    int col = w * 16 + li;

    short8 a[4];
#pragma unroll
    for (int kk = 0; kk < 4; ++kk)
        a[kk] = cvt8(feats + (size_t)arow * 128 + kk * 32 + kq * 8);
    __syncthreads();

    f32x4 am = (f32x4){0,0,0,0}, as = (f32x4){0,0,0,0};
#pragma unroll
    for (int kk = 0; kk < 4; ++kk) {
        int sw = (kk * 64 + kq * 16) ^ ((col & 7) << 4);
        short8 bm = *(const short8*)((char*)wa + col * 256 + sw);
        am = __builtin_amdgcn_mfma_f32_16x16x32_bf16(a[kk], bm, am, 0, 0, 0);
        short8 bs = *(const short8*)((char*)wl + col * 256 + sw);
        as = __builtin_amdgcn_mfma_f32_16x16x32_bf16(a[kk], bs, as, 0, 0, 0);
    }

    float ba = b_agg[col];
#pragma unroll
    for (int r = 0; r < 4; ++r) {
        int grow = r0 + kq * 4 + r;
        float t = am[r] + ba;
        t = t > 0.f ? t : 0.f;               // +0-safe relu (feeds u16-max)
        M0b[(size_t)grow * 128 + col] = f2bf(t);
        S[(size_t)grow * 128 + col] = as[r];
    }

    // block 0: dump linear bf16 weight copies for hop1mm / tail (consumed 2 kernels later)
    if (blockIdx.x == 0) {
#pragma unroll
        for (int it = 0; it < 8; ++it) {
            int i = tid + it * 512;              // 4096 chunks of 8 elems (W_lin 32768)
            *(short8*)(Wlb_ws + (size_t)i * 8) = cvt8(W_lin + (size_t)i * 8);
        }
#pragma unroll
        for (int it = 0; it < 4; ++it) {
            int i = tid + it * 512;              // 2048 chunks (W_agg 16384)
            *(short8*)(Wab_ws + (size_t)i * 8) = cvt8(W_agg + (size_t)i * 8);
        }
    }
}

// ---------------- agg1: one wave per TWO nodes; lane-parallel translate; shfl-broadcast gather ----
__global__ __launch_bounds__(256) void agg1_k(
    const int* __restrict__ nbd, const int* __restrict__ inv,
    const u16* __restrict__ M0b, const float* __restrict__ b_agg,
    unsigned* __restrict__ AGG1u) {
    int wave = blockIdx.x * 4 + (threadIdx.x >> 6);  // 25000 waves, 2 nodes each
    int lane = threadIdx.x & 63;
    int n0 = wave * 2;

    int nb = nbd[(size_t)n0 * DEG + lane];   // coalesced 256B (covers both nodes)
    int bi = inv[nb];                         // one vector gather
    unsigned long long warm = __ballot(bi >= 0);
    unsigned m0 = (unsigned)warm;
    unsigned m1 = (unsigned)(warm >> 32);

    float ba0 = b_agg[2 * lane], ba1 = b_agg[2 * lane + 1];
    ba0 = ba0 > 0.f ? ba0 : 0.f;
    ba1 = ba1 > 0.f ? ba1 : 0.f;
    unsigned rb = (unsigned)f2bf(ba0) | ((unsigned)f2bf(ba1) << 16);

    unsigned acc0 = (m0 != 0xffffffffu) ? rb : 0u;
    while (m0) {
        int pos = __builtin_ctz(m0);
        m0 &= m0 - 1;
        int bib = __shfl(bi, pos);
        acc0 = pkmax_u16(acc0, ((const unsigned*)(M0b + (size_t)bib * WIDTH))[lane]);
    }
    AGG1u[(size_t)n0 * 64 + lane] = acc0;

    unsigned acc1 = (m1 != 0xffffffffu) ? rb : 0u;
    while (m1) {
        int pos = __builtin_ctz(m1);
        m1 &= m1 - 1;
        int bib = __shfl(bi, 32 + pos);
        acc1 = pkmax_u16(acc1, ((const unsigned*)(M0b + (size_t)bib * WIDTH))[lane]);
    }
    AGG1u[(size_t)(n0 + 1) * 64 + lane] = acc1;
}

// ---------------- hop1mm v5: 64-row tiles, 3 blocks/CU, bf16 W from ws ----------------
// H1 = norm(relu(AGG1@Wlp.T + S[inv] + b_lin));  M1 = relu(H1@Wagg.T + b_agg)
// 782 blocks x 512 thr = 4 row-groups x 2 col-groups; LDS 50.7KB.
__global__ __launch_bounds__(512, 6) void hop1mm_k(
    const u16* __restrict__ AGG1, const int* __restrict__ inv,
    const float* __restrict__ S, const float* __restrict__ b_lin,
    const float* __restrict__ b_agg,
    const u16* __restrict__ Wlb, const u16* __restrict__ Wab,
    u16* __restrict__ H1g, u16* __restrict__ M1) {
    __shared__ u16 wlds[128 * 128];   // 32KB swizzled W (Wlp phase1, Wagg phase2)
    __shared__ u16 h1t[64 * 136];     // 17.4KB transpose buffer
    __shared__ float pnorm[2 * 64];   // [cg][row64]

    int tid = threadIdx.x;
    int w = tid >> 6, l = tid & 63, li = l & 15, kq = l >> 4;
    int rg = w >> 1, cg = w & 1;
    int row0 = blockIdx.x * 64;
    int lrow = rg * 16 + li;
    int arow = row0 + lrow;
    if (arow > N_NODES - 1) arow = N_NODES - 1;

    // A-frags early (hide under W staging)
    short8 af[4];
#pragma unroll
    for (int kk = 0; kk < 4; ++kk)
        af[kk] = *(const short8*)(AGG1 + (size_t)arow * 128 + kk * 32 + kq * 8);

    // stage Wlp (k-cols 128..255 of Wlb, bf16) into LDS, XOR-swizzled
#pragma unroll
    for (int it = 0; it < 4; ++it) {
        int c = tid + it * 512;
        int r = c >> 4, ch = c & 15;
        *(short8*)((char*)wlds + r * 256 + ((ch * 16) ^ ((r & 7) << 4))) =
            *(const short8*)(Wlb + (size_t)r * 256 + 128 + ch * 8);
    }
    __syncthreads();

    // GEMM1: h = AGG1 @ Wlp.T   (wave: 16 rows x 64 cols)
    f32x4 h[4];
#pragma unroll
    for (int n = 0; n < 4; ++n) h[n] = (f32x4){0,0,0,0};
#pragma unroll
    for (int kk = 0; kk < 4; ++kk)
#pragma unroll
        for (int n = 0; n < 4; ++n) {
            int col = cg * 64 + n * 16 + li;
            short8 b = *(const short8*)((char*)wlds + col * 256 +
                                        ((kk * 64 + kq * 16) ^ ((col & 7) << 4)));
            h[n] = __builtin_amdgcn_mfma_f32_16x16x32_bf16(af[kk], b, h[n], 0, 0, 0);
        }

    // epilogue 1: +S[inv], +b_lin, relu; partial norm across 2 cg; stash h1t; warm H1 write
    float blv[4];
#pragma unroll
    for (int n = 0; n < 4; ++n) blv[n] = b_lin[cg * 64 + n * 16 + li];

    float v[4][4];   // [r][n] static-indexed
    int biA[4];
#pragma unroll
    for (int r = 0; r < 4; ++r) {
        int lr = rg * 16 + kq * 4 + r;
        int grow = row0 + lr;
        int growc = grow < N_NODES ? grow : N_NODES - 1;
        biA[r] = inv[growc];
#pragma unroll
        for (int n = 0; n < 4; ++n) v[r][n] = h[n][r] + blv[n];
        if (biA[r] >= 0) {
#pragma unroll
            for (int n = 0; n < 4; ++n)
                v[r][n] += S[(size_t)biA[r] * 128 + cg * 64 + n * 16 + li];
        }
        float p = 0.f;
#pragma unroll
        for (int n = 0; n < 4; ++n) {
            v[r][n] = fmaxf(v[r][n], 0.f);
            p += v[r][n] * v[r][n];
        }
        p += __shfl_xor(p, 1);
        p += __shfl_xor(p, 2);
        p += __shfl_xor(p, 4);
        p += __shfl_xor(p, 8);
        if (li == 0) pnorm[cg * 64 + lr] = p;
    }
    __syncthreads();

#pragma unroll
    for (int r = 0; r < 4; ++r) {
        int lr = rg * 16 + kq * 4 + r;
        int grow = row0 + lr;
        float p = pnorm[lr] + pnorm[64 + lr];
        float sc = 1.0f / fmaxf(sqrtf(p), EPS);
        u16 vb[4];
#pragma unroll
        for (int n = 0; n < 4; ++n) vb[n] = f2bf(v[r][n] * sc);
        if (grow < N_NODES && biA[r] >= 0) {
#pragma unroll
            for (int n = 0; n < 4; ++n)
                H1g[(size_t)grow * 128 + cg * 64 + n * 16 + li] = vb[n];
        }
#pragma unroll
        for (int n = 0; n < 4; ++n) h1t[lr * 136 + cg * 64 + n * 16 + li] = vb[n];
    }
    __syncthreads();   // GEMM1 wlds reads + h1t writes complete

    // restage W: Wab (bf16, full 128 k-cols)
#pragma unroll
    for (int it = 0; it < 4; ++it) {
        int c = tid + it * 512;
        int r = c >> 4, ch = c & 15;
        *(short8*)((char*)wlds + r * 256 + ((ch * 16) ^ ((r & 7) << 4))) =
            *(const short8*)(Wab + (size_t)r * 128 + ch * 8);
    }
    __syncthreads();

    // GEMM2: M1 = relu(H1 @ Wagg.T + b_agg)
    short8 af2[4];
#pragma unroll
    for (int kk = 0; kk < 4; ++kk)
        af2[kk] = *(const short8*)(h1t + lrow * 136 + kk * 32 + kq * 8);

    f32x4 m[4];
#pragma unroll
    for (int n = 0; n < 4; ++n) m[n] = (f32x4){0,0,0,0};
#pragma unroll
    for (int kk = 0; kk < 4; ++kk)
#pragma unroll
        for (int n = 0; n < 4; ++n) {
            int col = cg * 64 + n * 16 + li;
            short8 b = *(const short8*)((char*)wlds + col * 256 +
                                        ((kk * 64 + kq * 16) ^ ((col & 7) << 4)));
            m[n] = __builtin_amdgcn_mfma_f32_16x16x32_bf16(af2[kk], b, m[n], 0, 0, 0);
        }

    float bav[4];
#pragma unroll
    for (int n = 0; n < 4; ++n) bav[n] = b_agg[cg * 64 + n * 16 + li];
#pragma unroll
    for (int r = 0; r < 4; ++r) {
        int grow = row0 + rg * 16 + kq * 4 + r;
        if (grow < N_NODES) {
#pragma unroll
            for (int n = 0; n < 4; ++n) {
                float t = m[n][r] + bav[n];
                t = t > 0.f ? t : 0.f;  // +0-safe relu (M1 feeds u16-max)
                M1[(size_t)grow * 128 + cg * 64 + n * 16 + li] = f2bf(t);
            }
        }
    }
}

// ---------------- tail: gather [H1 | max M1] into LDS + Wlb(bf16) staged; K=256 GEMM + norm ----
__global__ __launch_bounds__(512) void tail_k(
    const int* __restrict__ nbd, const int* __restrict__ node_idx,
    const u16* __restrict__ H1g, const u16* __restrict__ M1,
    const u16* __restrict__ Wlb, const float* __restrict__ b_lin,
    float* __restrict__ out) {
    __shared__ u16 wt[128 * 256];    // 64KB: full W_lin swizzled (512B rows)
    __shared__ u16 ab2[16 * 264];    // 16 rows x (256 + 8 pad) u16
    __shared__ float pn[128];
    __shared__ float pnt[16];

    int tid = threadIdx.x;
    int w = tid >> 6, l = tid & 63, li = l & 15, kq = l >> 4;
    int row0 = blockIdx.x * 16;

    // stage full W_lin (bf16 from ws), 512B rows, XOR-swizzled
#pragma unroll
    for (int it = 0; it < 8; ++it) {
        int c = tid + it * 512;            // 0..4095: 128 rows x 32 chunks(16B)
        int r = c >> 5, ch = c & 31;
        *(short8*)((char*)wt + r * 512 + ((ch * 16) ^ ((r & 7) << 4))) =
            *(const short8*)(Wlb + (size_t)r * 256 + ch * 8);
    }

    // gather phase: wave w gathers rows 2w, 2w+1
#pragma unroll
    for (int rr = 0; rr < 2; ++rr) {
        int lr = w * 2 + rr;
        int i = row0 + lr;
        int n = node_idx[i];  // wave-uniform
        unsigned hv = ((const unsigned*)(H1g + (size_t)n * 128))[l];
        *(unsigned*)((char*)ab2 + lr * 528 + l * 4) = hv;
        int nb = (l < DEG) ? nbd[(size_t)n * DEG + l] : 0;
        unsigned acc = 0;  // all M1 values >= +0
#pragma unroll
        for (int j = 0; j < DEG; ++j) {
            int bib = __shfl(nb, j);
            acc = pkmax_u16(acc, ((const unsigned*)(M1 + (size_t)bib * 128))[l]);
        }
        *(unsigned*)((char*)ab2 + lr * 528 + 256 + l * 4) = acc;
    }
    __syncthreads();

    int col = w * 16 + li;
    f32x4 acc4 = (f32x4){0,0,0,0};
#pragma unroll
    for (int kk = 0; kk < 8; ++kk) {
        short8 a = *(const short8*)((char*)ab2 + li * 528 + kk * 64 + kq * 16);
        short8 b = *(const short8*)((char*)wt + col * 512 +
                                    ((kk * 64 + kq * 16) ^ ((col & 7) << 4)));
        acc4 = __builtin_amdgcn_mfma_f32_16x16x32_bf16(a, b, acc4, 0, 0, 0);
    }

    float bl = b_lin[col];
    float v[4];
#pragma unroll
    for (int r = 0; r < 4; ++r) {
        v[r] = fmaxf(acc4[r] + bl, 0.f);
        float p = v[r] * v[r];
        p += __shfl_xor(p, 1);
        p += __shfl_xor(p, 2);
        p += __shfl_xor(p, 4);
        p += __shfl_xor(p, 8);
        if (li == 0) pn[w * 16 + kq * 4 + r] = p;
    }
    __syncthreads();
    if (tid < 16) {
        float s = 0.f;
#pragma unroll
        for (int ww = 0; ww < 8; ++ww) s += pn[ww * 16 + tid];
        pnt[tid] = s;
    }
    __syncthreads();
#pragma unroll
    for (int r = 0; r < 4; ++r) {
        int row = kq * 4 + r;
        float sc = 1.0f / fmaxf(sqrtf(pnt[row]), EPS);
        out[(size_t)(row0 + row) * 128 + col] = v[r] * sc;
    }
}

// ---------------- launch ----------------
extern "C" void kernel_launch(void* const* d_in, const int* in_sizes, int n_in,
                              void* d_out, int out_size, void* d_ws, size_t ws_size,
                              hipStream_t stream) {
    const int*   nbd      = (const int*)d_in[0];
    const int*   node_idx = (const int*)d_in[1];
    const float* feats    = (const float*)d_in[2];
    const float* W_agg    = (const float*)d_in[3];
    const float* b_agg    = (const float*)d_in[4];
    const float* W_lin    = (const float*)d_in[5];
    const float* b_lin    = (const float*)d_in[6];
    float* out = (float*)d_out;

    char* base = (char*)d_ws;
    size_t off = 0;
    int* inv  = (int*)(base + off);   off += 50048 * 4;
    u16* Wab  = (u16*)(base + off);   off += 16384 * 2;
    u16* Wlb  = (u16*)(base + off);   off += 32768 * 2;
    u16* M0b  = (u16*)(base + off);   off += (size_t)BATCH * 128 * 2;
    float* S  = (float*)(base + off); off += (size_t)BATCH * 128 * 4;
    u16* AGG1 = (u16*)(base + off);   off += (size_t)N_NODES * 128 * 2;
    u16* H1g  = (u16*)(base + off);   off += (size_t)N_NODES * 128 * 2;
    u16* M1   = (u16*)(base + off);   off += (size_t)N_NODES * 128 * 2;

    hipMemsetAsync(inv, 0xFF, 50048 * 4, stream);   // inv = -1

    head_k<<<BATCH / 16, 512, 0, stream>>>(feats, W_agg, W_lin, b_agg, node_idx, inv,
                                           M0b, S, Wab, Wlb);

    agg1_k<<<N_NODES / 8, 256, 0, stream>>>(nbd, inv, M0b, b_agg, (unsigned*)AGG1);

    hop1mm_k<<<(N_NODES + 63) / 64, 512, 0, stream>>>(
        AGG1, inv, S, b_lin, b_agg, Wlb, Wab, H1g, M1);

    tail_k<<<BATCH / 16, 512, 0, stream>>>(nbd, node_idx, H1g, M1, Wlb, b_lin, out);
}

// Round 15
// 54.757 us; speedup vs baseline: 3.0193x; 1.1146x over previous
//
#include <hip/hip_runtime.h>
#include <math.h>

#define N_NODES 50000
#define DEG 32
#define WIDTH 128
#define BATCH 4096
#define EPS 1e-12f

typedef __attribute__((ext_vector_type(8))) short short8;           // 8 bf16
typedef __attribute__((ext_vector_type(4))) float f32x4;            // MFMA acc
typedef unsigned short u16;

__device__ __forceinline__ u16 f2bf(float f) {
    unsigned x;
    __builtin_memcpy(&x, &f, 4);
    unsigned r = (x + 0x7fff + ((x >> 16) & 1)) >> 16;  // RNE
    return (u16)r;
}
__device__ __forceinline__ unsigned pkmax_u16(unsigned a, unsigned b) {
    unsigned lo = (a & 0xffffu) > (b & 0xffffu) ? (a & 0xffffu) : (b & 0xffffu);
    unsigned hi = (a >> 16) > (b >> 16) ? (a >> 16) : (b >> 16);
    return lo | (hi << 16);
}

// ---------------- prep: inv=-1, weights->bf16, packed relu(b_agg) ----------------
__global__ void prep_k(const float* __restrict__ W_agg, const float* __restrict__ W_lin,
                       const float* __restrict__ b_agg, int* __restrict__ inv,
                       u16* __restrict__ Wab, u16* __restrict__ Wlb,
                       unsigned* __restrict__ rbap) {
    int i = blockIdx.x * 256 + threadIdx.x;
    if (i < 50048) inv[i] = -1;
    int j = i - 50048;
    if (j >= 0 && j < 16384) Wab[j] = f2bf(W_agg[j]);
    int k = i - (50048 + 16384);
    if (k >= 0 && k < 32768) Wlb[k] = f2bf(W_lin[k]);
    if (i < 64) {
        float a = b_agg[2 * i], b = b_agg[2 * i + 1];
        a = a > 0.f ? a : 0.f;
        b = b > 0.f ? b : 0.f;
        rbap[i] = (unsigned)f2bf(a) | ((unsigned)f2bf(b) << 16);
    }
}

// ---------------- head: scatter inv; M0b(bf16)=relu(feats@Wagg.T+b_agg); S(f32)=feats@Wself.T
__global__ __launch_bounds__(512) void head_k(
    const float* __restrict__ feats, const u16* __restrict__ Wab, const u16* __restrict__ Wlb,
    const float* __restrict__ b_agg, const int* __restrict__ node_idx, int* __restrict__ inv,
    u16* __restrict__ M0b, float* __restrict__ S) {
    int tid = threadIdx.x;
    int gid = blockIdx.x * 512 + tid;
    if (gid < BATCH) atomicMax(&inv[node_idx[gid]], gid);  // last-write-wins scatter

    int w = tid >> 6, l = tid & 63, li = l & 15, kq = l >> 4;
    int r0 = blockIdx.x * 16;
    int arow = r0 + li;
    int col = w * 16 + li;

    f32x4 am = (f32x4){0,0,0,0}, as = (f32x4){0,0,0,0};
#pragma unroll
    for (int kk = 0; kk < 4; ++kk) {
        float4 a0 = *(const float4*)(feats + (size_t)arow * 128 + kk * 32 + kq * 8);
        float4 a1 = *(const float4*)(feats + (size_t)arow * 128 + kk * 32 + kq * 8 + 4);
        short8 a;
        a[0] = (short)f2bf(a0.x); a[1] = (short)f2bf(a0.y);
        a[2] = (short)f2bf(a0.z); a[3] = (short)f2bf(a0.w);
        a[4] = (short)f2bf(a1.x); a[5] = (short)f2bf(a1.y);
        a[6] = (short)f2bf(a1.z); a[7] = (short)f2bf(a1.w);
        short8 bm = *(const short8*)(Wab + (size_t)col * 128 + kk * 32 + kq * 8);
        am = __builtin_amdgcn_mfma_f32_16x16x32_bf16(a, bm, am, 0, 0, 0);
        short8 bs = *(const short8*)(Wlb + (size_t)col * 256 + kk * 32 + kq * 8);
        as = __builtin_amdgcn_mfma_f32_16x16x32_bf16(a, bs, as, 0, 0, 0);
    }

    float ba = b_agg[col];
#pragma unroll
    for (int r = 0; r < 4; ++r) {
        int grow = r0 + kq * 4 + r;
        float t = am[r] + ba;
        t = t > 0.f ? t : 0.f;               // +0-safe relu (feeds u16-max)
        M0b[(size_t)grow * 128 + col] = f2bf(t);
        S[(size_t)grow * 128 + col] = as[r];
    }
}

// ---------------- agg1: one wave per TWO nodes; lane-parallel translate; shfl-broadcast gather ----------------
__global__ __launch_bounds__(256) void agg1_k(
    const int* __restrict__ nbd, const int* __restrict__ inv,
    const u16* __restrict__ M0b, const unsigned* __restrict__ rbap,
    unsigned* __restrict__ AGG1u) {
    int wave = blockIdx.x * 4 + (threadIdx.x >> 6);  // 25000 waves, 2 nodes each
    int lane = threadIdx.x & 63;
    int n0 = wave * 2;

    int nb = nbd[(size_t)n0 * DEG + lane];   // coalesced 256B (covers both nodes)
    int bi = inv[nb];                         // one vector gather, 64 lanes in flight
    unsigned long long warm = __ballot(bi >= 0);
    unsigned m0 = (unsigned)warm;             // node n0 (lanes 0..31)
    unsigned m1 = (unsigned)(warm >> 32);     // node n0+1 (lanes 32..63)

    unsigned rb = rbap[lane];                 // packed relu(b_agg)

    unsigned acc0 = (m0 != 0xffffffffu) ? rb : 0u;
    while (m0) {
        int pos = __builtin_ctz(m0);
        m0 &= m0 - 1;
        int bib = __shfl(bi, pos);
        unsigned v = ((const unsigned*)(M0b + (size_t)bib * WIDTH))[lane];
        acc0 = pkmax_u16(acc0, v);
    }
    AGG1u[(size_t)n0 * 64 + lane] = acc0;

    unsigned acc1 = (m1 != 0xffffffffu) ? rb : 0u;
    while (m1) {
        int pos = __builtin_ctz(m1);
        m1 &= m1 - 1;
        int bib = __shfl(bi, 32 + pos);
        unsigned v = ((const unsigned*)(M0b + (size_t)bib * WIDTH))[lane];
        acc1 = pkmax_u16(acc1, v);
    }
    AGG1u[(size_t)(n0 + 1) * 64 + lane] = acc1;
}

// ---------------- hop1mm v3: W staged in LDS (XOR-swizzled), 128-row tiles, full-row waves ----------------
// H1 = norm(relu(AGG1@Wlp.T + S[inv] + b_lin));  M1 = relu(H1@Wagg.T + b_agg)
__global__ __launch_bounds__(512) void hop1mm_k(
    const u16* __restrict__ AGG1, const int* __restrict__ inv,
    const float* __restrict__ S, const float* __restrict__ b_lin,
    const float* __restrict__ b_agg,
    const u16* __restrict__ Wlb, const u16* __restrict__ Wab,
    u16* __restrict__ H1g, u16* __restrict__ M1) {
    __shared__ u16 wlds[128 * 128];   // 32KB swizzled W (Wlp phase1, Wab phase2)
    __shared__ u16 h1t[128 * 136];    // 34.8KB transpose buffer (pad 8 u16)

    int tid = threadIdx.x;
    int w = tid >> 6, l = tid & 63, li = l & 15, kq = l >> 4;
    int row0 = blockIdx.x * 128;
    int lrow = w * 16 + li;           // A-frag row (wave owns 16 full rows)
    int arow = row0 + lrow;
    if (arow > N_NODES - 1) arow = N_NODES - 1;

    // issue A-frag loads early (hide under W staging)
    short8 af[4];
#pragma unroll
    for (int kk = 0; kk < 4; ++kk)
        af[kk] = *(const short8*)(AGG1 + (size_t)arow * 128 + kk * 32 + kq * 8);

    // stage Wlp (k-cols 128..255 of Wlb) into LDS, XOR-swizzled rows
#pragma unroll
    for (int it = 0; it < 4; ++it) {
        int c = tid + it * 512;            // 16B chunk id, 0..2047
        int r = c >> 4;                    // W row (= output col)
        int cb = (c & 15) << 4;            // byte offset within 256B k-row
        short8 v = *(const short8*)(Wlb + (size_t)r * 256 + 128 + ((c & 15) << 3));
        *(short8*)((char*)wlds + r * 256 + (cb ^ ((r & 7) << 4))) = v;
    }
    __syncthreads();

    // GEMM1: h = AGG1 @ Wlp.T   (B from swizzled LDS: 2-way banks = free)
    f32x4 h[8];
#pragma unroll
    for (int n = 0; n < 8; ++n) h[n] = (f32x4){0,0,0,0};
#pragma unroll
    for (int kk = 0; kk < 4; ++kk)
#pragma unroll
        for (int n = 0; n < 8; ++n) {
            int col = n * 16 + li;
            short8 b = *(const short8*)((char*)wlds + col * 256 +
                                        ((kk * 64 + kq * 16) ^ ((col & 7) << 4)));
            h[n] = __builtin_amdgcn_mfma_f32_16x16x32_bf16(af[kk], b, h[n], 0, 0, 0);
        }

    // epilogue 1: +S[inv], +b_lin, relu, wave-internal row-norm; write warm H1; stash h1t
    float blv[8];
#pragma unroll
    for (int n = 0; n < 8; ++n) blv[n] = b_lin[n * 16 + li];

#pragma unroll
    for (int r = 0; r < 4; ++r) {
        int lr = w * 16 + kq * 4 + r;
        int grow = row0 + lr;
        int growc = grow < N_NODES ? grow : N_NODES - 1;
        int bi = inv[growc];
        float v[8];
#pragma unroll
        for (int n = 0; n < 8; ++n) v[n] = h[n][r] + blv[n];
        if (bi >= 0) {
#pragma unroll
            for (int n = 0; n < 8; ++n) v[n] += S[(size_t)bi * 128 + n * 16 + li];
        }
        float p = 0.f;
#pragma unroll
        for (int n = 0; n < 8; ++n) {
            v[n] = fmaxf(v[n], 0.f);
            p += v[n] * v[n];
        }
        p += __shfl_xor(p, 1);
        p += __shfl_xor(p, 2);
        p += __shfl_xor(p, 4);
        p += __shfl_xor(p, 8);
        float sc = 1.0f / fmaxf(sqrtf(p), EPS);
        u16 vb[8];
#pragma unroll
        for (int n = 0; n < 8; ++n) vb[n] = f2bf(v[n] * sc);
        if (grow < N_NODES && bi >= 0) {
#pragma unroll
            for (int n = 0; n < 8; ++n) H1g[(size_t)grow * 128 + n * 16 + li] = vb[n];
        }
#pragma unroll
        for (int n = 0; n < 8; ++n) h1t[lr * 136 + n * 16 + li] = vb[n];
    }
    __syncthreads();   // GEMM1 B-reads + h1t writes complete

    // restage W: Wab (full 128 k-cols), overwrites wlds
#pragma unroll
    for (int it = 0; it < 4; ++it) {
        int c = tid + it * 512;
        int r = c >> 4;
        int cb = (c & 15) << 4;
        short8 v = *(const short8*)(Wab + (size_t)r * 128 + ((c & 15) << 3));
        *(short8*)((char*)wlds + r * 256 + (cb ^ ((r & 7) << 4))) = v;
    }
    __syncthreads();

    // GEMM2: M1 = relu(H1 @ Wagg.T + b_agg);  A from h1t (2-way banks)
    short8 af2[4];
#pragma unroll
    for (int kk = 0; kk < 4; ++kk)
        af2[kk] = *(const short8*)(h1t + lrow * 136 + kk * 32 + kq * 8);

    f32x4 m[8];
#pragma unroll
    for (int n = 0; n < 8; ++n) m[n] = (f32x4){0,0,0,0};
#pragma unroll
    for (int kk = 0; kk < 4; ++kk)
#pragma unroll
        for (int n = 0; n < 8; ++n) {
            int col = n * 16 + li;
            short8 b = *(const short8*)((char*)wlds + col * 256 +
                                        ((kk * 64 + kq * 16) ^ ((col & 7) << 4)));
            m[n] = __builtin_amdgcn_mfma_f32_16x16x32_bf16(af2[kk], b, m[n], 0, 0, 0);
        }

    float bav[8];
#pragma unroll
    for (int n = 0; n < 8; ++n) bav[n] = b_agg[n * 16 + li];
#pragma unroll
    for (int r = 0; r < 4; ++r) {
        int grow = row0 + w * 16 + kq * 4 + r;
        if (grow < N_NODES) {
#pragma unroll
            for (int n = 0; n < 8; ++n) {
                float t = m[n][r] + bav[n];
                t = t > 0.f ? t : 0.f;  // +0-safe relu (M1 feeds u16-max)
                M1[(size_t)grow * 128 + n * 16 + li] = f2bf(t);
            }
        }
    }
}

// ---------------- tail fused: gather [H1 | max M1] into LDS, then K=256 GEMM + norm ----------------
// 256 blocks x 512 thr (8 waves); block owns 16 batch rows; wave w gathers rows 2w,2w+1.
__global__ __launch_bounds__(512) void tail_k(
    const int* __restrict__ nbd, const int* __restrict__ node_idx,
    const u16* __restrict__ H1g, const u16* __restrict__ M1,
    const u16* __restrict__ Wlb, const float* __restrict__ b_lin,
    float* __restrict__ out) {
    __shared__ u16 ab2[16 * 264];    // 16 rows x (256 + 8 pad) u16
    __shared__ float pn[128];
    __shared__ float pnt[16];

    int tid = threadIdx.x;
    int w = tid >> 6, l = tid & 63, li = l & 15, kq = l >> 4;
    int row0 = blockIdx.x * 16;

    // gather phase
#pragma unroll
    for (int rr = 0; rr < 2; ++rr) {
        int lr = w * 2 + rr;
        int i = row0 + lr;
        int n = node_idx[i];  // wave-uniform
        unsigned hv = ((const unsigned*)(H1g + (size_t)n * 128))[l];
        *(unsigned*)((char*)ab2 + lr * 528 + l * 4) = hv;
        int nb = (l < DEG) ? nbd[(size_t)n * DEG + l] : 0;
        unsigned acc = 0;  // all M1 values >= +0
#pragma unroll
        for (int j = 0; j < DEG; ++j) {
            int bib = __shfl(nb, j);
            unsigned v = ((const unsigned*)(M1 + (size_t)bib * 128))[l];
            acc = pkmax_u16(acc, v);
        }
        *(unsigned*)((char*)ab2 + lr * 528 + 256 + l * 4) = acc;
    }
    __syncthreads();

    // GEMM: out cols w*16+li, K=256; A from LDS (2-way banks), B from L2
    int col = w * 16 + li;
    f32x4 acc4 = (f32x4){0,0,0,0};
#pragma unroll
    for (int kk = 0; kk < 8; ++kk) {
        short8 a = *(const short8*)((char*)ab2 + li * 528 + kk * 64 + kq * 16);
        short8 b = *(const short8*)(Wlb + (size_t)col * 256 + kk * 32 + kq * 8);
        acc4 = __builtin_amdgcn_mfma_f32_16x16x32_bf16(a, b, acc4, 0, 0, 0);
    }

    float bl = b_lin[col];
    float v[4];
#pragma unroll
    for (int r = 0; r < 4; ++r) {
        v[r] = fmaxf(acc4[r] + bl, 0.f);
        float p = v[r] * v[r];
        p += __shfl_xor(p, 1);
        p += __shfl_xor(p, 2);
        p += __shfl_xor(p, 4);
        p += __shfl_xor(p, 8);
        if (li == 0) pn[w * 16 + kq * 4 + r] = p;
    }
    __syncthreads();
    if (tid < 16) {
        float s = 0.f;
#pragma unroll
        for (int ww = 0; ww < 8; ++ww) s += pn[ww * 16 + tid];
        pnt[tid] = s;
    }
    __syncthreads();
#pragma unroll
    for (int r = 0; r < 4; ++r) {
        int row = kq * 4 + r;
        float sc = 1.0f / fmaxf(sqrtf(pnt[row]), EPS);
        out[(size_t)(row0 + row) * 128 + col] = v[r] * sc;
    }
}

// ---------------- launch ----------------
extern "C" void kernel_launch(void* const* d_in, const int* in_sizes, int n_in,
                              void* d_out, int out_size, void* d_ws, size_t ws_size,
                              hipStream_t stream) {
    const int*   nbd      = (const int*)d_in[0];
    const int*   node_idx = (const int*)d_in[1];
    const float* feats    = (const float*)d_in[2];
    const float* W_agg    = (const float*)d_in[3];
    const float* b_agg    = (const float*)d_in[4];
    const float* W_lin    = (const float*)d_in[5];
    const float* b_lin    = (const float*)d_in[6];
    float* out = (float*)d_out;

    char* base = (char*)d_ws;
    size_t off = 0;
    int* inv       = (int*)(base + off);      off += 50048 * 4;
    u16* Wab       = (u16*)(base + off);      off += 16384 * 2;
    u16* Wlb       = (u16*)(base + off);      off += 32768 * 2;
    unsigned* rbap = (unsigned*)(base + off); off += 64 * 4;
    u16* M0b       = (u16*)(base + off);      off += (size_t)BATCH * 128 * 2;
    float* S       = (float*)(base + off);    off += (size_t)BATCH * 128 * 4;
    u16* AGG1      = (u16*)(base + off);      off += (size_t)N_NODES * 128 * 2;
    u16* H1g       = (u16*)(base + off);      off += (size_t)N_NODES * 128 * 2;
    u16* M1        = (u16*)(base + off);      off += (size_t)N_NODES * 128 * 2;

    prep_k<<<(50048 + 16384 + 32768 + 255) / 256, 256, 0, stream>>>(
        W_agg, W_lin, b_agg, inv, Wab, Wlb, rbap);

    head_k<<<BATCH / 16, 512, 0, stream>>>(feats, Wab, Wlb, b_agg, node_idx, inv, M0b, S);

    agg1_k<<<N_NODES / 8, 256, 0, stream>>>(nbd, inv, M0b, rbap, (unsigned*)AGG1);

    hop1mm_k<<<(N_NODES + 127) / 128, 512, 0, stream>>>(
        AGG1, inv, S, b_lin, b_agg, Wlb, Wab, H1g, M1);

    tail_k<<<BATCH / 16, 512, 0, stream>>>(nbd, node_idx, H1g, M1, Wlb, b_lin, out);
}